// Round 13
// baseline (1233.896 us; speedup 1.0000x reference)
//
#include <hip/hip_runtime.h>

typedef _Float16 f16;
typedef _Float16 f16x4 __attribute__((ext_vector_type(4)));
typedef _Float16 f16x8 __attribute__((ext_vector_type(8)));
typedef float f32x4 __attribute__((ext_vector_type(4)));
typedef int i32x4 __attribute__((ext_vector_type(4)));

#define TLEN 2048
#define TPAD 2050
#define NCOL 640            // 160 units x 4 gates, col = u*4 + G
#define GSTEP (16 * NCOL)   // f16 elements per timestep in gates3 [t][b][col]
#define NPROD 240           // producer blocks (bid 16..255)
#define NCHUNK 256          // 2048 / 8 timesteps per chunk
#define K1 1.4426950408889634f
#define K2 2.8853900817779268f

// ---------------------------------------------------------------------------
// Per-row |max| of w_hh for i8 quantization scales.
// ---------------------------------------------------------------------------
__global__ __launch_bounds__(64) void rowmax_k(const float* __restrict__ w_hh,
                                               float* __restrict__ rowmax)
{
    const int r = blockIdx.x * 64 + threadIdx.x;
    if (r < 600) {
        float m = 0.f;
        for (int k = 0; k < 150; ++k) m = fmaxf(m, fabsf(w_hh[r * 150 + k]));
        rowmax[r] = m;
    }
}

// ---------------------------------------------------------------------------
// Prep (unchanged from r12): wihf f16 fragments of w_ih (pre-scaled per gate),
// whhq i8 fragments of w_hh (per-row quantized, K padded 150->192),
// biasp pre-scaled combined bias, dsc per-col dequant scales.
// ---------------------------------------------------------------------------
__global__ void prep_weights(const float* __restrict__ w_ih,
                             const float* __restrict__ w_hh,
                             const float* __restrict__ b_ih,
                             const float* __restrict__ b_hh,
                             const float* __restrict__ rowmax,
                             f16* __restrict__ wihf, signed char* __restrict__ whhq,
                             float* __restrict__ biasp, float* __restrict__ dsc)
{
    const int idx = blockIdx.x * blockDim.x + threadIdx.x;
    const int stride = gridDim.x * blockDim.x;
    for (int i = idx; i < 40 * 5 * 64 * 8; i += stride) {
        const int e = i & 7;
        const int lane = (i >> 3) & 63;
        const int kt = (i >> 9) % 5;
        const int nt = i / 2560;
        const int colg = nt * 16 + (lane & 15);
        const int u = colg >> 2, G = colg & 3;
        const int k = kt * 32 + (lane >> 4) * 8 + e;
        const float sc = (G == 2) ? K2 : -K1;
        f16 vi = (f16)0.f;
        if (u < 150 && k < 144) vi = (f16)(w_ih[(G * 150 + u) * 144 + k] * sc);
        wihf[i] = vi;
    }
    for (int i = idx; i < 40 * 3 * 64 * 16; i += stride) {
        const int byte = i & 15;
        const int lane = (i >> 4) & 63;
        const int kt = (i >> 10) % 3;
        const int nt = i / 3072;
        const int colg = nt * 16 + (lane & 15);
        const int u = colg >> 2, G = colg & 3;
        const int k = kt * 64 + (lane >> 4) * 16 + byte;
        signed char q = 0;
        if (u < 150 && k < 150) {
            const int row = G * 150 + u;
            const float rm = rowmax[row];
            if (rm > 0.f)
                q = (signed char)(int)rintf(w_hh[row * 150 + k] * (127.f / rm));
        }
        whhq[i] = q;
    }
    for (int i = idx; i < NCOL; i += stride) {
        const int u = i >> 2, G = i & 3;
        const float sc = (G == 2) ? K2 : -K1;
        biasp[i] = (u < 150) ? (b_ih[G * 150 + u] + b_hh[G * 150 + u]) * sc : 0.f;
        dsc[i]   = (u < 150) ? sc * rowmax[G * 150 + u] * (1.f / 16129.f) : 0.f;
    }
}

// ---------------------------------------------------------------------------
// Scan step (i8 MFMA, r12 structure + shared-denominator activation).
// ---------------------------------------------------------------------------
__device__ __forceinline__ void lstm_stepQ(
    int t, int cur, f16x4& pfu, f16x4& pfc, const f16*& pLoad,
    const i32x4 (&afrag)[5][3], const f32x4& scv,
    signed char* hqs, f16* hfs, float& cst,
    int grp, int sel, bool wr, int u)
{
    const f16x4 pnew = *(const f16x4*)pLoad;
    pLoad += GSTEP;

    const signed char* hr = hqs + cur * 192 + grp * 16;
    i32x4 bf[3];
    #pragma unroll
    for (int kt = 0; kt < 3; ++kt)
        bf[kt] = *(const i32x4*)(hr + kt * 64);

    float gx0 = (float)pfu[0], gx1 = (float)pfu[1];
    float gx2 = (float)pfu[2], gx3 = (float)pfu[3];
    pfc = pnew;

    const i32x4 zc = {0, 0, 0, 0};
    i32x4 acc[5];
    #pragma unroll
    for (int i = 0; i < 5; ++i)
        acc[i] = __builtin_amdgcn_mfma_i32_16x16x64_i8(afrag[i][0], bf[0], zc, 0, 0, 0);
    #pragma unroll
    for (int kt = 1; kt < 3; ++kt)
        #pragma unroll
        for (int i = 0; i < 5; ++i)
            acc[i] = __builtin_amdgcn_mfma_i32_16x16x64_i8(afrag[i][kt], bf[kt], acc[i], 0, 0, 0);

    int s0 = acc[0][0], s1 = acc[0][1], s2 = acc[0][2], s3 = acc[0][3];
    #pragma unroll
    for (int i = 1; i < 5; ++i) {
        const bool p = (sel == i);
        s0 = p ? acc[i][0] : s0;
        s1 = p ? acc[i][1] : s1;
        s2 = p ? acc[i][2] : s2;
        s3 = p ? acc[i][3] : s3;
    }

    const float g0 = fmaf((float)s0, scv[0], gx0);
    const float g1 = fmaf((float)s1, scv[1], gx1);
    const float g2 = fmaf((float)s2, scv[2], gx2);
    const float g3 = fmaf((float)s3, scv[3], gx3);

    // Shared-denominator activation: 5 exp2 + 3 rcp.  All paths finite:
    // inf denominators give rcp->0 with finite numerators.
    const float ei = __builtin_amdgcn_exp2f(g0);                // e^{-i}
    const float ef = __builtin_amdgcn_exp2f(g1);                // e^{-f}
    const float eg = __builtin_amdgcn_exp2f(fminf(g2, 38.f));   // e^{2g}
    const float eo = __builtin_amdgcn_exp2f(g3);                // e^{-o}
    const float dig = (1.f + ei) * (eg + 1.f);
    const float c = cst * __builtin_amdgcn_rcpf(1.f + ef)
                  + (eg - 1.f) * __builtin_amdgcn_rcpf(dig);
    cst = c;
    const float ec = __builtin_amdgcn_exp2f(fminf(K2 * c, 80.f));
    const float h = (ec - 1.f) * __builtin_amdgcn_rcpf((1.f + eo) * (ec + 1.f));

    if (wr) hqs[(cur ^ 1) * 192 + u] = (signed char)(int)rintf(127.f * h);
    if (t == TLEN - 1 && wr) hfs[u] = (f16)h;

    asm volatile("s_waitcnt lgkmcnt(0)" ::: "memory");
    __builtin_amdgcn_s_barrier();
    __builtin_amdgcn_sched_barrier(0);
}

// ---------------------------------------------------------------------------
// MEGA kernel: 256 blocks x 512 threads (one per CU -> all co-resident).
//   blocks 0..15   : persistent i8 LSTM scan, one batch row each.
//   blocks 16..255 : producers; each produces chunks of 8 timesteps
//                    (conv 17->4 + ReLU into LDS, then gates GEMM to global),
//                    then releases flags[chunk] at agent scope.
// The scan acquires flags[ch] before prefetching into a chunk, pre-loading
// the NEXT chunk's flag 8 steps early so steady-state polling is off the
// critical path.  Cross-XCD visibility: per-thread __threadfence before the
// release store; acquire loads invalidate consumer caches.
// ---------------------------------------------------------------------------
__global__ __launch_bounds__(512, 1) void mega(
    const float* __restrict__ inp, const float* __restrict__ cw,
    const float* __restrict__ cb,
    const f16* __restrict__ wihf, const float* __restrict__ biasp,
    f16* __restrict__ gates3,
    const signed char* __restrict__ whhq, const float* __restrict__ dsc,
    const float* __restrict__ last_w, const float* __restrict__ last_b,
    int* __restrict__ flags, float* __restrict__ out)
{
    const int bid = blockIdx.x;
    const int tid = threadIdx.x, w = tid >> 6, lane = tid & 63;
    const int col = lane & 15, grp = lane >> 4;

    if (bid >= 16) {
        // ------------------------------ producer ------------------------------
        __shared__ float s_in[16][1092];           // 16 images, +4 pad (banks)
        __shared__ __align__(16) f16 s_y[8][16][168];  // conv out, padded row
        __shared__ float s_w[612];
        for (int i = tid; i < 612; i += 512) s_w[i] = cw[i];

        // w_ih fragments for this wave's 5 tiles + bias
        f16x8 bfr[5][5];
        float bb[5];
        #pragma unroll
        for (int i = 0; i < 5; ++i) {
            const int nt = w * 5 + i;
            const f16* wf = wihf + (size_t)(nt * 5) * 512;
            #pragma unroll
            for (int kt = 0; kt < 5; ++kt)
                bfr[i][kt] = *(const f16x8*)(wf + kt * 512 + lane * 8);
            bb[i] = biasp[nt * 16 + col];
        }
        // conv role (fixed per thread): cb_b = batch, unit -> (oc, oy)
        const int cb_b = tid & 15, unit = tid >> 4;      // unit 0..31
        const int oc = unit / 6, oy = unit % 6;          // valid if unit<24
        const float cbias = (unit < 24) ? cb[oc] : 0.f;
        __syncthreads();

        for (int ch = bid - 16; ch < NCHUNK; ch += NPROD) {
            const int t0 = ch * 8;
            for (int tl = 0; tl < 8; ++tl) {
                const int t = t0 + tl;
                __syncthreads();   // previous tl's conv done before restaging
                {   // stage 16 images (32 threads per image, coalesced)
                    const int si = tid >> 5, l2 = tid & 31;
                    const float* ip = inp + ((size_t)si * TLEN + t) * 1088;
                    for (int k = l2; k < 1088; k += 32) s_in[si][k] = ip[k];
                }
                __syncthreads();
                if (unit < 24) {
                    const float* wp = s_w + oc * 153;
                    float acc[6] = {cbias, cbias, cbias, cbias, cbias, cbias};
                    #pragma unroll 1
                    for (int ic = 0; ic < 17; ++ic) {
                        const float* rowb = &s_in[cb_b][ic * 64 + oy * 8];
                        #pragma unroll
                        for (int ky = 0; ky < 3; ++ky) {
                            const float* r = rowb + ky * 8;
                            const float w0 = wp[ic * 9 + ky * 3 + 0];
                            const float w1 = wp[ic * 9 + ky * 3 + 1];
                            const float w2 = wp[ic * 9 + ky * 3 + 2];
                            #pragma unroll
                            for (int ox = 0; ox < 6; ++ox)
                                acc[ox] += r[ox] * w0 + r[ox + 1] * w1 + r[ox + 2] * w2;
                        }
                    }
                    #pragma unroll
                    for (int ox = 0; ox < 6; ++ox)
                        s_y[tl][cb_b][oc * 36 + oy * 6 + ox] = (f16)fmaxf(acc[ox], 0.f);
                } else if (unit == 24) {
                    #pragma unroll
                    for (int k = 0; k < 16; ++k) s_y[tl][cb_b][144 + k] = (f16)0.f;
                }
            }
            __syncthreads();
            // gates GEMM for the 8 timesteps (A from LDS y, B resident)
            for (int tl = 0; tl < 8; ++tl) {
                const int t = t0 + tl;
                f16x8 a[5];
                #pragma unroll
                for (int kt = 0; kt < 5; ++kt)
                    a[kt] = *(const f16x8*)(&s_y[tl][col][kt * 32 + grp * 8]);
                #pragma unroll
                for (int i = 0; i < 5; ++i) {
                    f32x4 acc = {0.f, 0.f, 0.f, 0.f};
                    #pragma unroll
                    for (int kt = 0; kt < 5; ++kt)
                        acc = __builtin_amdgcn_mfma_f32_16x16x32_f16(a[kt], bfr[i][kt], acc, 0, 0, 0);
                    const int colg = (w * 5 + i) * 16 + col;
                    #pragma unroll
                    for (int r = 0; r < 4; ++r)
                        gates3[((size_t)(t * 16 + grp * 4 + r)) * NCOL + colg] =
                            (f16)(acc[r] + bb[i]);
                }
            }
            __threadfence();       // make this thread's stores agent-visible
            __syncthreads();       // all threads' fences done
            if (tid == 0)
                __hip_atomic_store(&flags[ch], 1, __ATOMIC_RELEASE,
                                   __HIP_MEMORY_SCOPE_AGENT);
        }
        return;
    }

    // -------------------------------- scan --------------------------------
    __shared__ __align__(16) signed char hq[2 * 192];
    __shared__ __align__(16) f16 hf[160];
    const int b = bid;
    const int sel = (col < 5) ? col : ((col < 10) ? col - 5 : ((col < 15) ? col - 10 : 0));
    const bool wr = (col < 5);
    const int u = 20 * w + 4 * sel + grp;

    for (int i = tid; i < 2 * 192; i += 512) hq[i] = 0;

    i32x4 afrag[5][3];
    #pragma unroll
    for (int i = 0; i < 5; ++i)
        #pragma unroll
        for (int kt = 0; kt < 3; ++kt)
            afrag[i][kt] =
                *(const i32x4*)(whhq + (size_t)(((5 * w + i) * 3 + kt) * 64 + lane) * 16);

    const f32x4 scv = *(const f32x4*)(dsc + 4 * u);
    float cst = 0.f;
    __syncthreads();

    // Wait for chunk 0, then preload chunk 1's flag (checked 8 steps later).
    while (__hip_atomic_load(&flags[0], __ATOMIC_ACQUIRE, __HIP_MEMORY_SCOPE_AGENT) == 0)
        __builtin_amdgcn_s_sleep(2);
    int pend = __hip_atomic_load(&flags[1], __ATOMIC_ACQUIRE, __HIP_MEMORY_SCOPE_AGENT);

    const f16* gbu = gates3 + (size_t)b * NCOL + 80 * w + 16 * sel + 4 * grp;
    f16x4 pA = *(const f16x4*)(gbu);
    f16x4 pB = *(const f16x4*)(gbu + (size_t)1 * GSTEP);
    const f16* pLoad = gbu + (size_t)2 * GSTEP;

    #pragma unroll 1
    for (int tb = 0; tb < TLEN; tb += 2) {
        const int tn = tb + 2;
        if ((tn & 7) == 0 && tn < TLEN) {
            const int ch = tn >> 3;
            while (pend == 0) {
                pend = __hip_atomic_load(&flags[ch], __ATOMIC_ACQUIRE,
                                         __HIP_MEMORY_SCOPE_AGENT);
                if (!pend) __builtin_amdgcn_s_sleep(2);
            }
            pend = (ch + 1 < NCHUNK)
                 ? __hip_atomic_load(&flags[ch + 1], __ATOMIC_ACQUIRE,
                                     __HIP_MEMORY_SCOPE_AGENT)
                 : 1;
        }
        lstm_stepQ(tb,     0, pA, pA, pLoad, afrag, scv, hq, hf, cst, grp, sel, wr, u);
        lstm_stepQ(tb + 1, 1, pB, pB, pLoad, afrag, scv, hq, hf, cst, grp, sel, wr, u);
    }

    if (tid < 2) {
        float s = last_b[tid];
        for (int j = 0; j < 150; ++j)
            s += (float)hf[j] * last_w[tid * 150 + j];
        out[b * 2 + tid] = s;
    }
}

// ---------------------------------------------------------------------------
extern "C" void kernel_launch(void* const* d_in, const int* in_sizes, int n_in,
                              void* d_out, int out_size, void* d_ws, size_t ws_size,
                              hipStream_t stream) {
    const float* inp    = (const float*)d_in[0];
    const float* conv_w = (const float*)d_in[1];
    const float* conv_b = (const float*)d_in[2];
    const float* w_ih   = (const float*)d_in[3];
    const float* w_hh   = (const float*)d_in[4];
    const float* b_ih   = (const float*)d_in[5];
    const float* b_hh   = (const float*)d_in[6];
    const float* last_w = (const float*)d_in[7];
    const float* last_b = (const float*)d_in[8];
    float* out = (float*)d_out;

    char* ws = (char*)d_ws;
    size_t off = 0;
    f16*   gates3 = (f16*)(ws + off);  off += (size_t)TPAD * 16 * NCOL * 2; // 41,984,000
    f16*   wihf   = (f16*)(ws + off);  off += 204800;
    signed char* whhq = (signed char*)(ws + off); off += 122880;
    float* biasp  = (float*)(ws + off); off += 2560;
    float* dsc    = (float*)(ws + off); off += 2560;
    float* rowmax = (float*)(ws + off); off += 2560;
    int*   flags  = (int*)(ws + off);   off += (NCHUNK + 4) * 4;

    hipMemsetAsync(flags, 0, (NCHUNK + 4) * 4, stream);
    rowmax_k<<<10, 64, 0, stream>>>(w_hh, rowmax);
    prep_weights<<<120, 256, 0, stream>>>(w_ih, w_hh, b_ih, b_hh, rowmax,
                                          wihf, whhq, biasp, dsc);
    mega<<<256, 512, 0, stream>>>(inp, conv_w, conv_b, wihf, biasp, gates3,
                                  whhq, dsc, last_w, last_b, flags, out);
}

// Round 14
// 1003.893 us; speedup vs baseline: 1.2291x; 1.2291x over previous
//
#include <hip/hip_runtime.h>

typedef _Float16 f16;
typedef _Float16 f16x4 __attribute__((ext_vector_type(4)));
typedef _Float16 f16x8 __attribute__((ext_vector_type(8)));
typedef float f32x4 __attribute__((ext_vector_type(4)));
typedef int i32x4 __attribute__((ext_vector_type(4)));

#define TLEN 2048
#define TPAD 2050
#define NCOL 640            // 160 units x 4 gates, col = u*4 + G
#define GSTEP (16 * NCOL)   // f16 elements per timestep in gates3 [t][b][col]
#define SPITCH 1099         // odd LDS pitch for staged images (full bank spread)
#define K1 1.4426950408889634f
#define K2 2.8853900817779268f

// ---------------------------------------------------------------------------
// Per-row |max| of w_hh for i8 quantization scales.
// ---------------------------------------------------------------------------
__global__ __launch_bounds__(64) void rowmax_k(const float* __restrict__ w_hh,
                                               float* __restrict__ rowmax)
{
    const int r = blockIdx.x * 64 + threadIdx.x;
    if (r < 600) {
        float m = 0.f;
        for (int k = 0; k < 150; ++k) m = fmaxf(m, fabsf(w_hh[r * 150 + k]));
        rowmax[r] = m;
    }
}

// ---------------------------------------------------------------------------
// Prep: wihf f16 fragments of w_ih (pre-scaled per gate: i,f,o -K1; g +K2),
// whhq i8 fragments of w_hh (per-row quantized, K padded 150->192),
// biasp pre-scaled combined bias, dsc per-col dequant scales.
// ---------------------------------------------------------------------------
__global__ void prep_weights(const float* __restrict__ w_ih,
                             const float* __restrict__ w_hh,
                             const float* __restrict__ b_ih,
                             const float* __restrict__ b_hh,
                             const float* __restrict__ rowmax,
                             f16* __restrict__ wihf, signed char* __restrict__ whhq,
                             float* __restrict__ biasp, float* __restrict__ dsc)
{
    const int idx = blockIdx.x * blockDim.x + threadIdx.x;
    const int stride = gridDim.x * blockDim.x;
    for (int i = idx; i < 40 * 5 * 64 * 8; i += stride) {
        const int e = i & 7;
        const int lane = (i >> 3) & 63;
        const int kt = (i >> 9) % 5;
        const int nt = i / 2560;
        const int colg = nt * 16 + (lane & 15);
        const int u = colg >> 2, G = colg & 3;
        const int k = kt * 32 + (lane >> 4) * 8 + e;
        const float sc = (G == 2) ? K2 : -K1;
        f16 vi = (f16)0.f;
        if (u < 150 && k < 144) vi = (f16)(w_ih[(G * 150 + u) * 144 + k] * sc);
        wihf[i] = vi;
    }
    for (int i = idx; i < 40 * 3 * 64 * 16; i += stride) {
        const int byte = i & 15;
        const int lane = (i >> 4) & 63;
        const int kt = (i >> 10) % 3;
        const int nt = i / 3072;
        const int colg = nt * 16 + (lane & 15);
        const int u = colg >> 2, G = colg & 3;
        const int k = kt * 64 + (lane >> 4) * 16 + byte;
        signed char q = 0;
        if (u < 150 && k < 150) {
            const int row = G * 150 + u;
            const float rm = rowmax[row];
            if (rm > 0.f)
                q = (signed char)(int)rintf(w_hh[row * 150 + k] * (127.f / rm));
        }
        whhq[i] = q;
    }
    for (int i = idx; i < NCOL; i += stride) {
        const int u = i >> 2, G = i & 3;
        const float sc = (G == 2) ? K2 : -K1;
        biasp[i] = (u < 150) ? (b_ih[G * 150 + u] + b_hh[G * 150 + u]) * sc : 0.f;
        dsc[i]   = (u < 150) ? sc * rowmax[G * 150 + u] * (1.f / 16129.f) : 0.f;
    }
}

// ---------------------------------------------------------------------------
// Fused conv+gates GEMM: 256 blocks x 512 threads, one block per 8-timestep
// chunk (structure proven correct as the r13 producer; no flags/fences).
// Per timestep: stage 16 images into LDS (odd pitch 1099 -> no bank
// conflicts), conv 17->4 + ReLU into s_y (f16, K padded to 160), then 8
// timesteps of gates GEMM with w_ih fragments resident.
// Output gates3 [t][b(16)][col(640)] f16.
// ---------------------------------------------------------------------------
__global__ __launch_bounds__(512, 1) void conv_gemm(
    const float* __restrict__ inp, const float* __restrict__ cw,
    const float* __restrict__ cb,
    const f16* __restrict__ wihf, const float* __restrict__ biasp,
    f16* __restrict__ gates3)
{
    __shared__ float s_in[16][SPITCH];
    __shared__ __align__(16) f16 s_y[8][16][168];
    __shared__ float s_w[612];
    const int tid = threadIdx.x, w = tid >> 6, lane = tid & 63;
    const int col = lane & 15, grp = lane >> 4;
    for (int i = tid; i < 612; i += 512) s_w[i] = cw[i];

    // w_ih fragments for this wave's 5 tiles + bias
    f16x8 bfr[5][5];
    float bb[5];
    #pragma unroll
    for (int i = 0; i < 5; ++i) {
        const int nt = w * 5 + i;
        const f16* wf = wihf + (size_t)(nt * 5) * 512;
        #pragma unroll
        for (int kt = 0; kt < 5; ++kt)
            bfr[i][kt] = *(const f16x8*)(wf + kt * 512 + lane * 8);
        bb[i] = biasp[nt * 16 + col];
    }
    // conv role: cb_b = batch, unit -> (oc, oy)
    const int cb_b = tid & 15, unit = tid >> 4;      // unit 0..31
    const int oc = unit / 6, oy = unit % 6;          // valid if unit < 24
    const float cbias = (unit < 24) ? cb[oc] : 0.f;
    __syncthreads();

    const int t0 = blockIdx.x * 8;
    for (int tl = 0; tl < 8; ++tl) {
        const int t = t0 + tl;
        __syncthreads();   // previous tl's conv reads done before restaging
        {   // stage 16 images (32 threads per image, coalesced)
            const int si = tid >> 5, l2 = tid & 31;
            const float* ip = inp + ((size_t)si * TLEN + t) * 1088;
            for (int k = l2; k < 1088; k += 32) s_in[si][k] = ip[k];
        }
        __syncthreads();
        if (unit < 24) {
            const float* wp = s_w + oc * 153;
            float acc[6] = {cbias, cbias, cbias, cbias, cbias, cbias};
            #pragma unroll 1
            for (int ic = 0; ic < 17; ++ic) {
                const float* rowb = &s_in[cb_b][ic * 64 + oy * 8];
                #pragma unroll
                for (int ky = 0; ky < 3; ++ky) {
                    const float* r = rowb + ky * 8;
                    const float w0 = wp[ic * 9 + ky * 3 + 0];
                    const float w1 = wp[ic * 9 + ky * 3 + 1];
                    const float w2 = wp[ic * 9 + ky * 3 + 2];
                    #pragma unroll
                    for (int ox = 0; ox < 6; ++ox)
                        acc[ox] += r[ox] * w0 + r[ox + 1] * w1 + r[ox + 2] * w2;
                }
            }
            #pragma unroll
            for (int ox = 0; ox < 6; ++ox)
                s_y[tl][cb_b][oc * 36 + oy * 6 + ox] = (f16)fmaxf(acc[ox], 0.f);
        } else if (unit == 24) {
            #pragma unroll
            for (int k = 0; k < 16; ++k) s_y[tl][cb_b][144 + k] = (f16)0.f;
        }
    }
    __syncthreads();
    // gates GEMM for the 8 timesteps (A from LDS s_y, B resident)
    for (int tl = 0; tl < 8; ++tl) {
        const int t = t0 + tl;
        f16x8 a[5];
        #pragma unroll
        for (int kt = 0; kt < 5; ++kt)
            a[kt] = *(const f16x8*)(&s_y[tl][col][kt * 32 + grp * 8]);
        #pragma unroll
        for (int i = 0; i < 5; ++i) {
            f32x4 acc = {0.f, 0.f, 0.f, 0.f};
            #pragma unroll
            for (int kt = 0; kt < 5; ++kt)
                acc = __builtin_amdgcn_mfma_f32_16x16x32_f16(a[kt], bfr[i][kt], acc, 0, 0, 0);
            const int colg = (w * 5 + i) * 16 + col;
            #pragma unroll
            for (int r = 0; r < 4; ++r)
                gates3[((size_t)(t * 16 + grp * 4 + r)) * NCOL + colg] =
                    (f16)(acc[r] + bb[i]);
        }
    }
}

// ---------------------------------------------------------------------------
// Scan step (i8 MFMA, r12 structure + 3-rcp shared-denominator activation).
// ---------------------------------------------------------------------------
__device__ __forceinline__ void lstm_stepQ(
    int t, int cur, f16x4& pfu, f16x4& pfc, const f16*& pLoad,
    const i32x4 (&afrag)[5][3], const f32x4& scv,
    signed char* hqs, f16* hfs, float& cst,
    int grp, int sel, bool wr, int u)
{
    // 1) Issue next-next-step gates load first (longest latency).
    const f16x4 pnew = *(const f16x4*)pLoad;
    pLoad += GSTEP;

    // 2) B-fragment reads: 3 x b128 of quantized h (broadcast, conflict-free).
    const signed char* hr = hqs + cur * 192 + grp * 16;
    i32x4 bf[3];
    #pragma unroll
    for (int kt = 0; kt < 3; ++kt)
        bf[kt] = *(const i32x4*)(hr + kt * 64);

    // 3) In the read shadow: convert this step's unit-gates (f16->f32).
    float gx0 = (float)pfu[0], gx1 = (float)pfu[1];
    float gx2 = (float)pfu[2], gx3 = (float)pfu[3];
    pfc = pnew;

    // 4) i8 MFMA: 5 tiles x 3 kt, integer C-init 0.
    const i32x4 zc = {0, 0, 0, 0};
    i32x4 acc[5];
    #pragma unroll
    for (int i = 0; i < 5; ++i)
        acc[i] = __builtin_amdgcn_mfma_i32_16x16x64_i8(afrag[i][0], bf[0], zc, 0, 0, 0);
    #pragma unroll
    for (int kt = 1; kt < 3; ++kt)
        #pragma unroll
        for (int i = 0; i < 5; ++i)
            acc[i] = __builtin_amdgcn_mfma_i32_16x16x64_i8(afrag[i][kt], bf[kt], acc[i], 0, 0, 0);

    // 5) Select this lane's tile.
    int s0 = acc[0][0], s1 = acc[0][1], s2 = acc[0][2], s3 = acc[0][3];
    #pragma unroll
    for (int i = 1; i < 5; ++i) {
        const bool p = (sel == i);
        s0 = p ? acc[i][0] : s0;
        s1 = p ? acc[i][1] : s1;
        s2 = p ? acc[i][2] : s2;
        s3 = p ? acc[i][3] : s3;
    }

    // 6) Dequant + add gates_x (dsc carries gate prescale/sign).
    const float g0 = fmaf((float)s0, scv[0], gx0);
    const float g1 = fmaf((float)s1, scv[1], gx1);
    const float g2 = fmaf((float)s2, scv[2], gx2);
    const float g3 = fmaf((float)s3, scv[3], gx3);

    // 7) Shared-denominator activation: 5 exp2 + 3 rcp; all paths finite.
    const float ei = __builtin_amdgcn_exp2f(g0);                // e^{-i}
    const float ef = __builtin_amdgcn_exp2f(g1);                // e^{-f}
    const float eg = __builtin_amdgcn_exp2f(fminf(g2, 38.f));   // e^{2g}
    const float eo = __builtin_amdgcn_exp2f(g3);                // e^{-o}
    const float dig = (1.f + ei) * (eg + 1.f);
    const float c = cst * __builtin_amdgcn_rcpf(1.f + ef)
                  + (eg - 1.f) * __builtin_amdgcn_rcpf(dig);
    cst = c;
    const float ec = __builtin_amdgcn_exp2f(fminf(K2 * c, 80.f));
    const float h = (ec - 1.f) * __builtin_amdgcn_rcpf((1.f + eo) * (ec + 1.f));

    // 8) Quantize + write h (i8); f16 copy only on the last step.
    if (wr) hqs[(cur ^ 1) * 192 + u] = (signed char)(int)rintf(127.f * h);
    if (t == TLEN - 1 && wr) hfs[u] = (f16)h;

    // 9) Drain LDS ops only; ONE raw barrier per step (vmcnt stays hot).
    asm volatile("s_waitcnt lgkmcnt(0)" ::: "memory");
    __builtin_amdgcn_s_barrier();
    __builtin_amdgcn_sched_barrier(0);
}

// ---------------------------------------------------------------------------
// Batch-parallel persistent i8 LSTM scan: 16 WGs (one batch row each), 512
// threads = 8 waves = 2/SIMD.  Standalone (no producer coupling): plain
// global reads of gates3, prefetched 2 steps ahead, vmcnt never drained.
// ---------------------------------------------------------------------------
__global__ __launch_bounds__(512, 1) void lstm_scan(
    const f16* __restrict__ gates3, const signed char* __restrict__ whhq,
    const float* __restrict__ dsc,
    const float* __restrict__ last_w, const float* __restrict__ last_b,
    float* __restrict__ out)
{
    __shared__ __align__(16) signed char hq[2 * 192];
    __shared__ __align__(16) f16 hf[160];
    const int b = blockIdx.x;
    const int tid = threadIdx.x, w = tid >> 6, lane = tid & 63;
    const int col = lane & 15, grp = lane >> 4;
    const int sel = (col < 5) ? col : ((col < 10) ? col - 5 : ((col < 15) ? col - 10 : 0));
    const bool wr = (col < 5);
    const int u = 20 * w + 4 * sel + grp;

    for (int i = tid; i < 2 * 192; i += 512) hq[i] = 0;

    i32x4 afrag[5][3];
    #pragma unroll
    for (int i = 0; i < 5; ++i)
        #pragma unroll
        for (int kt = 0; kt < 3; ++kt)
            afrag[i][kt] =
                *(const i32x4*)(whhq + (size_t)(((5 * w + i) * 3 + kt) * 64 + lane) * 16);

    const f32x4 scv = *(const f32x4*)(dsc + 4 * u);
    float cst = 0.f;
    __syncthreads();

    const f16* gbu = gates3 + (size_t)b * NCOL + 80 * w + 16 * sel + 4 * grp;
    f16x4 pA = *(const f16x4*)(gbu);
    f16x4 pB = *(const f16x4*)(gbu + (size_t)1 * GSTEP);
    const f16* pLoad = gbu + (size_t)2 * GSTEP;

    #pragma unroll 1
    for (int tb = 0; tb < TLEN; tb += 2) {
        lstm_stepQ(tb,     0, pA, pA, pLoad, afrag, scv, hq, hf, cst, grp, sel, wr, u);
        lstm_stepQ(tb + 1, 1, pB, pB, pLoad, afrag, scv, hq, hf, cst, grp, sel, wr, u);
    }

    if (tid < 2) {
        float s = last_b[tid];
        for (int j = 0; j < 150; ++j)
            s += (float)hf[j] * last_w[tid * 150 + j];
        out[b * 2 + tid] = s;
    }
}

// ---------------------------------------------------------------------------
extern "C" void kernel_launch(void* const* d_in, const int* in_sizes, int n_in,
                              void* d_out, int out_size, void* d_ws, size_t ws_size,
                              hipStream_t stream) {
    const float* inp    = (const float*)d_in[0];
    const float* conv_w = (const float*)d_in[1];
    const float* conv_b = (const float*)d_in[2];
    const float* w_ih   = (const float*)d_in[3];
    const float* w_hh   = (const float*)d_in[4];
    const float* b_ih   = (const float*)d_in[5];
    const float* b_hh   = (const float*)d_in[6];
    const float* last_w = (const float*)d_in[7];
    const float* last_b = (const float*)d_in[8];
    float* out = (float*)d_out;

    char* ws = (char*)d_ws;
    size_t off = 0;
    f16*   gates3 = (f16*)(ws + off);  off += (size_t)TPAD * 16 * NCOL * 2; // 41,984,000
    f16*   wihf   = (f16*)(ws + off);  off += 204800;
    signed char* whhq = (signed char*)(ws + off); off += 122880;
    float* biasp  = (float*)(ws + off); off += 2560;
    float* dsc    = (float*)(ws + off); off += 2560;
    float* rowmax = (float*)(ws + off); off += 2560;

    rowmax_k<<<10, 64, 0, stream>>>(w_hh, rowmax);
    prep_weights<<<120, 256, 0, stream>>>(w_ih, w_hh, b_ih, b_hh, rowmax,
                                          wihf, whhq, biasp, dsc);
    conv_gemm<<<256, 512, 0, stream>>>(inp, conv_w, conv_b, wihf, biasp, gates3);
    lstm_scan<<<16, 512, 0, stream>>>(gates3, whhq, dsc, last_w, last_b, out);
}